// Round 1
// baseline (144.360 us; speedup 1.0000x reference)
//
#include <hip/hip_runtime.h>
#include <math.h>

#define LOG2E  1.44269504088896340736f
#define LN2    0.69314718055994530942f
#define LOG2PI 1.8378770664093453f

#define N 2048
#define D 64

// ---------------------------------------------------------------------------
// K1: precompute per-(j,d) factors.
//   packed[j*64+d] = {mean, niv2, c22, 0} where
//     niv2 = -0.5*exp(-lv)*log2e   (so arg2 = diff^2*niv2 + c22 = a*log2e)
//     c22  = -0.5*(lv+LOG2PI)*log2e
//   pT[d][j] = niv2, qT[d][j] = -2*mean*niv2 (transposed for K2 coalescing)
//   r[j] = sum_d (mean^2*niv2 + c22)
// One wave per row j, lane = d.
// ---------------------------------------------------------------------------
__global__ __launch_bounds__(256) void k1_precompute(
    const float* __restrict__ z_mean, const float* __restrict__ z_lv,
    float4* __restrict__ packed, float* __restrict__ pT,
    float* __restrict__ qT, float* __restrict__ r)
{
    int wave = threadIdx.x >> 6;
    int lane = threadIdx.x & 63;
    int j = blockIdx.x * 4 + wave;
    int idx = j * D + lane;
    float mean = z_mean[idx];
    float lv   = z_lv[idx];
    float niv2 = -0.5f * expf(-lv) * LOG2E;
    float c22  = -0.5f * (lv + LOG2PI) * LOG2E;
    packed[idx] = make_float4(mean, niv2, c22, 0.0f);
    pT[lane * N + j] = niv2;
    qT[lane * N + j] = -2.0f * mean * niv2;
    float t = fmaf(mean * mean, niv2, c22);
    #pragma unroll
    for (int off = 32; off; off >>= 1) t += __shfl_xor(t, off, 64);
    if (lane == 0) r[j] = t;
}

// ---------------------------------------------------------------------------
// K3: per-(i,d) sum over j of 2^(a*log2e), fixed max M=0 (safe for this data:
// a <= max c2 ~ 0.83 nats, a_max >= ~-30 nats -> no overflow/underflow).
//   lqp[i] = ln2 * sum_d log2( sum_j 2^{arg2(i,j,d)} )
// Block: 8 i's, 8 waves each owning a 256-wide j-slice, lane = d.
// ---------------------------------------------------------------------------
__global__ __launch_bounds__(512) void k3_perd(
    const float* __restrict__ z, const float4* __restrict__ packed,
    float* __restrict__ lqp)
{
    __shared__ float sm[8][8][D];   // [i][wave][d] partial sums
    int lane = threadIdx.x & 63;
    int w    = threadIdx.x >> 6;    // 0..7
    int i0   = blockIdx.x * 8;

    float zr[8], s[8];
    #pragma unroll
    for (int i = 0; i < 8; ++i) {
        zr[i] = z[(i0 + i) * D + lane];
        s[i]  = 0.0f;
    }

    const float4* pk = packed + (size_t)w * 256 * D + lane;
    #pragma unroll 4
    for (int jj = 0; jj < 256; ++jj) {
        float4 p = pk[jj * D];      // {mean, niv2, c22, -}
        #pragma unroll
        for (int i = 0; i < 8; ++i) {
            float diff = zr[i] - p.x;
            float arg  = fmaf(diff * diff, p.y, p.z);
            s[i] += exp2f(arg);
        }
    }

    #pragma unroll
    for (int i = 0; i < 8; ++i) sm[i][w][lane] = s[i];
    __syncthreads();

    // wave w finishes row i0+w
    float tot = 0.0f;
    #pragma unroll
    for (int w2 = 0; w2 < 8; ++w2) tot += sm[w][w2][lane];
    float t = __log2f(tot);
    #pragma unroll
    for (int off = 32; off; off >>= 1) t += __shfl_xor(t, off, 64);
    if (lane == 0) lqp[i0 + w] = LN2 * t;
}

// ---------------------------------------------------------------------------
// K2: log_qz[i] = ln2 * log2sumexp2_j( b2[i,j] ),
//   b2[i,j] = sum_d z2[i,d]*pT[d,j] + z[i,d]*qT[d,j] + r[j]
// Block: 8 i's; thread owns j in {tid + 256k}; register tile acc[8i][8k].
// Loads of pT/qT are coalesced (consecutive lanes -> consecutive j).
// ---------------------------------------------------------------------------
__global__ __launch_bounds__(256) void k2_logqz(
    const float* __restrict__ z, const float* __restrict__ pT,
    const float* __restrict__ qT, const float* __restrict__ r,
    float* __restrict__ lq)
{
    __shared__ float zs[8][D], z2s[8][D];
    __shared__ float pm[8][256], ps[8][256];
    int tid = threadIdx.x;
    int i0  = blockIdx.x * 8;

    for (int t = tid; t < 8 * D; t += 256) {
        int i = t >> 6, d = t & 63;
        float v = z[(i0 + i) * D + d];
        zs[i][d] = v;
        z2s[i][d] = v * v;
    }
    __syncthreads();

    float acc[8][8];
    #pragma unroll
    for (int i = 0; i < 8; ++i)
        #pragma unroll
        for (int k = 0; k < 8; ++k) acc[i][k] = 0.0f;

    for (int d = 0; d < D; ++d) {
        float zv[8], z2v[8];
        #pragma unroll
        for (int i = 0; i < 8; ++i) { z2v[i] = z2s[i][d]; zv[i] = zs[i][d]; }
        #pragma unroll
        for (int k = 0; k < 8; ++k) {
            int jj = tid + 256 * k;
            float p = pT[d * N + jj];
            float q = qT[d * N + jj];
            #pragma unroll
            for (int i = 0; i < 8; ++i)
                acc[i][k] = fmaf(z2v[i], p, fmaf(zv[i], q, acc[i][k]));
        }
    }

    // per-thread online LSE (log2 domain) over its 8 j's, per i
    float m[8], se[8];
    #pragma unroll
    for (int i = 0; i < 8; ++i) { m[i] = -1e30f; se[i] = 0.0f; }
    #pragma unroll
    for (int k = 0; k < 8; ++k) {
        float rk = r[tid + 256 * k];
        #pragma unroll
        for (int i = 0; i < 8; ++i) {
            float b  = acc[i][k] + rk;
            float mn = fmaxf(m[i], b);
            se[i] = se[i] * exp2f(m[i] - mn) + exp2f(b - mn);
            m[i]  = mn;
        }
    }
    #pragma unroll
    for (int i = 0; i < 8; ++i) { pm[i][tid] = m[i]; ps[i][tid] = se[i]; }
    __syncthreads();

    if (tid < 8) {
        float mm = pm[tid][0], ss = ps[tid][0];
        for (int t = 1; t < 256; ++t) {
            float m2 = pm[tid][t], s2 = ps[tid][t];
            float mn = fmaxf(mm, m2);
            ss = ss * exp2f(mm - mn) + s2 * exp2f(m2 - mn);
            mm = mn;
        }
        lq[i0 + tid] = LN2 * (mm + __log2f(ss));
    }
}

// ---------------------------------------------------------------------------
// K4: out = mean_i(lqp[i] - lq[i])
// ---------------------------------------------------------------------------
__global__ __launch_bounds__(256) void k4_final(
    const float* __restrict__ lqp, const float* __restrict__ lq,
    float* __restrict__ out)
{
    __shared__ float red[256];
    int tid = threadIdx.x;
    float t = 0.0f;
    for (int k = tid; k < N; k += 256) t += lqp[k] - lq[k];
    red[tid] = t;
    __syncthreads();
    #pragma unroll
    for (int off = 128; off; off >>= 1) {
        if (tid < off) red[tid] += red[tid + off];
        __syncthreads();
    }
    if (tid == 0) out[0] = red[0] * (1.0f / (float)N);
}

extern "C" void kernel_launch(void* const* d_in, const int* in_sizes, int n_in,
                              void* d_out, int out_size, void* d_ws, size_t ws_size,
                              hipStream_t stream)
{
    const float* z      = (const float*)d_in[0];
    const float* z_mean = (const float*)d_in[1];
    const float* z_lv   = (const float*)d_in[2];
    float* out = (float*)d_out;

    float* ws = (float*)d_ws;
    float4* packed = (float4*)ws;                 // N*D*4 floats = 2 MB
    float* pT  = ws + (size_t)N * D * 4;          // N*D
    float* qT  = pT + (size_t)N * D;              // N*D
    float* r   = qT + (size_t)N * D;              // N
    float* lqp = r + N;                           // N
    float* lq  = lqp + N;                         // N

    k1_precompute<<<N / 4, 256, 0, stream>>>(z_mean, z_lv, packed, pT, qT, r);
    k3_perd<<<N / 8, 512, 0, stream>>>(z, packed, lqp);
    k2_logqz<<<N / 8, 256, 0, stream>>>(z, pT, qT, r, lq);
    k4_final<<<1, 256, 0, stream>>>(lqp, lq, out);
}

// Round 2
// 80.669 us; speedup vs baseline: 1.7895x; 1.7895x over previous
//
#include <hip/hip_runtime.h>
#include <math.h>

#define LOG2E  1.44269504088896340736f
#define LN2    0.69314718055994530942f
#define LOG2PI 1.8378770664093453f

#define N 2048
#define D 64

// fast single-instruction transcendentals (v_exp_f32 / v_log_f32)
__device__ __forceinline__ float fexp2(float x) { return __builtin_amdgcn_exp2f(x); }
__device__ __forceinline__ float flog2(float x) { return __builtin_amdgcn_logf(x); }

// ---------------------------------------------------------------------------
// K1: per-(j,d) factors. a_ijd*log2e = z2*p + z*q + r2 with
//   p  = -0.5*exp(-lv)*log2e
//   q  = -2*mean*p
//   r2 = mean^2*p - 0.5*(lv+LOG2PI)*log2e
// packed[j*64+d] = {p, q, r2, 0}; pT[d][j]=p, qT[d][j]=q (transposed for K2);
// r[j] = sum_d r2.
// ---------------------------------------------------------------------------
__global__ __launch_bounds__(256) void k1_precompute(
    const float* __restrict__ z_mean, const float* __restrict__ z_lv,
    float4* __restrict__ packed, float* __restrict__ pT,
    float* __restrict__ qT, float* __restrict__ r)
{
    int wave = threadIdx.x >> 6;
    int lane = threadIdx.x & 63;
    int j = blockIdx.x * 4 + wave;
    int idx = j * D + lane;
    float mean = z_mean[idx];
    float lv   = z_lv[idx];
    float p   = -0.5f * fexp2(-lv * LOG2E) * LOG2E;
    float q   = -2.0f * mean * p;
    float r2  = fmaf(mean * mean, p, -0.5f * (lv + LOG2PI) * LOG2E);
    packed[idx] = make_float4(p, q, r2, 0.0f);
    pT[lane * N + j] = p;
    qT[lane * N + j] = q;
    float t = r2;
    #pragma unroll
    for (int off = 32; off; off >>= 1) t += __shfl_xor(t, off, 64);
    if (lane == 0) r[j] = t;
}

// ---------------------------------------------------------------------------
// K3: lqp[i] = ln2 * sum_d log2( sum_j 2^{z2*p + z*q + r2} )   (fixed max M=0,
// safe: per-(i,d) args bounded in [-~5000, ~1.2]; underflow-to-0 harmless).
// Block: 1024 thr = 16 waves; 8 i's; wave w owns a 128-wide j slice; lane = d.
// ---------------------------------------------------------------------------
__global__ __launch_bounds__(1024) void k3_perd(
    const float* __restrict__ z, const float4* __restrict__ packed,
    float* __restrict__ lqp)
{
    __shared__ float sm[8][16][D];   // [i][wave][d] partial sums, 32 KB
    int lane = threadIdx.x & 63;
    int w    = threadIdx.x >> 6;     // 0..15
    int i0   = blockIdx.x * 8;

    float zr[8], z2r[8], s[8];
    #pragma unroll
    for (int i = 0; i < 8; ++i) {
        zr[i]  = z[(i0 + i) * D + lane];
        z2r[i] = zr[i] * zr[i];
        s[i]   = 0.0f;
    }

    const float4* pk = packed + (size_t)w * 128 * D + lane;
    #pragma unroll 4
    for (int jj = 0; jj < 128; ++jj) {
        float4 c = pk[(size_t)jj * D];   // {p, q, r2, -}
        #pragma unroll
        for (int i = 0; i < 8; ++i) {
            float arg = fmaf(z2r[i], c.x, fmaf(zr[i], c.y, c.z));
            s[i] += fexp2(arg);
        }
    }

    #pragma unroll
    for (int i = 0; i < 8; ++i) sm[i][w][lane] = s[i];
    __syncthreads();

    if (w < 8) {   // wave w finishes row i0+w
        float tot = 0.0f;
        #pragma unroll
        for (int w2 = 0; w2 < 16; ++w2) tot += sm[w][w2][lane];
        float t = flog2(tot);
        #pragma unroll
        for (int off = 32; off; off >>= 1) t += __shfl_xor(t, off, 64);
        if (lane == 0) lqp[i0 + w] = LN2 * t;
    }
}

// ---------------------------------------------------------------------------
// K2: log_qz[i] = ln2 * LSE2_j( b2[i,j] ),  b2 = sum_d z2*pT + z*qT + r[j].
// Online max kept (b2 range ~ -240 log2 risks denormal flush with fixed max).
// Block: 512 thr; 8 i's; thread owns j in {tid + 512k, k<4}; acc[8][4].
// ---------------------------------------------------------------------------
__global__ __launch_bounds__(512) void k2_logqz(
    const float* __restrict__ z, const float* __restrict__ pT,
    const float* __restrict__ qT, const float* __restrict__ r,
    float* __restrict__ lq)
{
    __shared__ float zs[8][D], z2s[8][D];
    __shared__ float pm[8][512], ps[8][512];
    int tid = threadIdx.x;
    int i0  = blockIdx.x * 8;

    {
        int i = tid >> 6, d = tid & 63;
        float v = z[(i0 + i) * D + d];
        zs[i][d]  = v;
        z2s[i][d] = v * v;
    }
    __syncthreads();

    float acc[8][4];
    #pragma unroll
    for (int i = 0; i < 8; ++i)
        #pragma unroll
        for (int k = 0; k < 4; ++k) acc[i][k] = 0.0f;

    for (int d = 0; d < D; ++d) {
        float zv[8], z2v[8];
        #pragma unroll
        for (int i = 0; i < 8; ++i) { z2v[i] = z2s[i][d]; zv[i] = zs[i][d]; }
        #pragma unroll
        for (int k = 0; k < 4; ++k) {
            int jj = tid + 512 * k;
            float p = pT[d * N + jj];
            float q = qT[d * N + jj];
            #pragma unroll
            for (int i = 0; i < 8; ++i)
                acc[i][k] = fmaf(z2v[i], p, fmaf(zv[i], q, acc[i][k]));
        }
    }

    // per-thread online LSE (log2 domain) over its 4 j's, per i
    float m[8], se[8];
    #pragma unroll
    for (int i = 0; i < 8; ++i) { m[i] = -1e30f; se[i] = 0.0f; }
    #pragma unroll
    for (int k = 0; k < 4; ++k) {
        float rk = r[tid + 512 * k];
        #pragma unroll
        for (int i = 0; i < 8; ++i) {
            float b  = acc[i][k] + rk;
            float mn = fmaxf(m[i], b);
            se[i] = se[i] * fexp2(m[i] - mn) + fexp2(b - mn);
            m[i]  = mn;
        }
    }
    #pragma unroll
    for (int i = 0; i < 8; ++i) { pm[i][tid] = m[i]; ps[i][tid] = se[i]; }
    __syncthreads();

    // wave w reduces row i0+w: 512 partials -> 64 lanes x 8 -> shuffle merge
    int w = tid >> 6, lane = tid & 63;
    float mm = -1e30f, ss = 0.0f;
    #pragma unroll
    for (int c = 0; c < 8; ++c) {
        float m2 = pm[w][lane + 64 * c];
        float s2 = ps[w][lane + 64 * c];
        float mn = fmaxf(mm, m2);
        ss = ss * fexp2(mm - mn) + s2 * fexp2(m2 - mn);
        mm = mn;
    }
    #pragma unroll
    for (int off = 32; off; off >>= 1) {
        float m2 = __shfl_xor(mm, off, 64);
        float s2 = __shfl_xor(ss, off, 64);
        float mn = fmaxf(mm, m2);
        ss = ss * fexp2(mm - mn) + s2 * fexp2(m2 - mn);
        mm = mn;
    }
    if (lane == 0) lq[i0 + w] = LN2 * (mm + flog2(ss));
}

// ---------------------------------------------------------------------------
// K4: out = mean_i(lqp[i] - lq[i])
// ---------------------------------------------------------------------------
__global__ __launch_bounds__(256) void k4_final(
    const float* __restrict__ lqp, const float* __restrict__ lq,
    float* __restrict__ out)
{
    __shared__ float red[256];
    int tid = threadIdx.x;
    float t = 0.0f;
    for (int k = tid; k < N; k += 256) t += lqp[k] - lq[k];
    red[tid] = t;
    __syncthreads();
    #pragma unroll
    for (int off = 128; off; off >>= 1) {
        if (tid < off) red[tid] += red[tid + off];
        __syncthreads();
    }
    if (tid == 0) out[0] = red[0] * (1.0f / (float)N);
}

extern "C" void kernel_launch(void* const* d_in, const int* in_sizes, int n_in,
                              void* d_out, int out_size, void* d_ws, size_t ws_size,
                              hipStream_t stream)
{
    const float* z      = (const float*)d_in[0];
    const float* z_mean = (const float*)d_in[1];
    const float* z_lv   = (const float*)d_in[2];
    float* out = (float*)d_out;

    float* ws = (float*)d_ws;
    float4* packed = (float4*)ws;                 // N*D*4 floats = 2 MB
    float* pT  = ws + (size_t)N * D * 4;          // N*D
    float* qT  = pT + (size_t)N * D;              // N*D
    float* r   = qT + (size_t)N * D;              // N
    float* lqp = r + N;                           // N
    float* lq  = lqp + N;                         // N

    k1_precompute<<<N / 4, 256, 0, stream>>>(z_mean, z_lv, packed, pT, qT, r);
    k3_perd<<<N / 8, 1024, 0, stream>>>(z, packed, lqp);
    k2_logqz<<<N / 8, 512, 0, stream>>>(z, pT, qT, r, lq);
    k4_final<<<1, 256, 0, stream>>>(lqp, lq, out);
}